// Round 9
// baseline (30703.650 us; speedup 1.0000x reference)
//
#include <hip/hip_runtime.h>
#include <hip/hip_bf16.h>
#include <math.h>

// DARQN: conv×3 -> per-step additive attention + LSTM scan (T=2048) -> q head.
// R12: ONE exchange per step.
//  - gates = sum_w ( ctx[Kw]@Wih[:,Kw]^T + h[Kw]@Whh[:,Kw]^T ), Kw = 32 dims
//    per WG: LSTM weights partitioned by INPUT dim (same 128KB/WG registers).
//  - each WG computes a full 1024-dim partial-gate vector pg_w locally, then
//    ONE all-reduce of pg (f32 seq-words, double-buffered pgm[2][8][1024]).
//  - cell update REPLICATED in every WG (deterministic: identical published
//    f32 bits summed in identical order) -> h,c local everywhere -> the h
//    broadcast leg is DELETED.
//  - attention column-sliced: staging/logits/softmax-stats replicated (A reads
//    8x, prefetched a step ahead; vecs reads NOT replicated - 32 cols/WG);
//    softmax uses stride-32 lane mapping (bank-conflict-free).
//  - transport = R4's proven scheme (relaxed agent-scope stores, uniform
//    poll-gather where the detecting iteration IS the data, s_sleep pacing).
//  - double buffer kills the overwrite race; lockstep gather bounds WG skew
//    to 1 step; guards break visibly (wrong answer), never hang.

#define T_FRAMES 2048
#define NI 49
#define HID 256
#define NA 18
#define NWG 8

typedef __bf16 v8bf __attribute__((ext_vector_type(8)));
typedef float v4f __attribute__((ext_vector_type(4)));

// ---------------- workspace layout (bytes) ----------------
static constexpr size_t OFF_FM1   = 0;                  // fm1 [2048,32,20,20] f32; reused for A [2048,49,256] f32
static constexpr size_t OFF_FM2   = 104857600;          // fm2 [2048,64,9,9] f32; reused for comm block
static constexpr size_t OFF_VECS  = 147324928;          // vecs [2048,49,256] f32
static constexpr size_t OFF_W2B   = 250085376;          // bf16 256*256
static constexpr size_t OFF_WIHB  = OFF_W2B  + 131072;  // bf16 1024*256
static constexpr size_t OFF_WHHB  = OFF_WIHB + 524288;  // bf16 1024*256
static constexpr size_t OFF_W1T   = OFF_WHHB + 524288;  // f32 256*256
// comm block aliases fm2 (dead after conv3): pgm u64[2][8][1024] (seq|f32)
static constexpr size_t OFF_COMM  = OFF_FM2;
static constexpr int PG_WORDS = 2 * NWG * 1024;         // 16384

// ---------------- weight prep ----------------
__global__ void prep_weights(const float* __restrict__ w2, const float* __restrict__ wih,
                             const float* __restrict__ whh, const float* __restrict__ w1,
                             __bf16* w2b, __bf16* wihb, __bf16* whhb, float* w1t) {
  int idx = blockIdx.x * 256 + threadIdx.x;
  int stride = gridDim.x * 256;
  for (int i = idx; i < 65536; i += stride) w2b[i] = (__bf16)w2[i];
  for (int i = idx; i < 262144; i += stride) wihb[i] = (__bf16)wih[i];
  for (int i = idx; i < 262144; i += stride) whhb[i] = (__bf16)whh[i];
  for (int i = idx; i < 65536; i += stride) {
    int r = i >> 8, c = i & 255;
    w1t[c * 256 + r] = w1[i];
  }
}

// ---------------- conv1: [T,1,84,84] -> [T,32,20,20], k8 s4 ----------------
__global__ void conv1_k(const float* __restrict__ x, const float* __restrict__ w,
                        const float* __restrict__ b, float* __restrict__ y) {
  int idx = blockIdx.x * 256 + threadIdx.x;
  if (idx >= T_FRAMES * 32 * 20 * 20) return;
  int xx = idx % 20, yy = (idx / 20) % 20, o = (idx / 400) % 32, t = idx / 12800;
  const float* xp = x + t * 7056 + yy * 4 * 84 + xx * 4;
  const float* wp = w + o * 64;
  float acc = b[o];
  #pragma unroll
  for (int ky = 0; ky < 8; ky++)
    #pragma unroll
    for (int kx = 0; kx < 8; kx++)
      acc += xp[ky * 84 + kx] * wp[ky * 8 + kx];
  y[idx] = fmaxf(acc, 0.f);
}

// ---------------- conv2: [T,32,20,20] -> [T,64,9,9], k4 s2 ----------------
__global__ __launch_bounds__(256) void conv2_k(const float* __restrict__ fm1, const float* __restrict__ w,
                                               const float* __restrict__ b, float* __restrict__ fm2) {
  __shared__ float xs[32 * 400];
  int t = blockIdx.x, tid = threadIdx.x;
  for (int i = tid; i < 12800; i += 256) xs[i] = fm1[t * 12800 + i];
  __syncthreads();
  int o = tid >> 2, q = tid & 3;
  int p0 = q * 21, p1 = (p0 + 21 < 81) ? p0 + 21 : 81;
  int ob[21];
  #pragma unroll
  for (int i2 = 0; i2 < 21; i2++) {
    int p = p0 + i2; if (p > 80) p = 80;
    int yy = p / 9, xx2 = p - yy * 9;
    ob[i2] = yy * 40 + xx2 * 2;
  }
  float acc[21];
  #pragma unroll
  for (int i2 = 0; i2 < 21; i2++) acc[i2] = 0.f;
  for (int c = 0; c < 32; c++) {
    int cbase = c * 400;
    for (int ky = 0; ky < 4; ky++)
      for (int kx = 0; kx < 4; kx++) {
        float wgt = w[((o * 32 + c) * 4 + ky) * 4 + kx];
        int kyo = ky * 20 + kx;
        #pragma unroll
        for (int i2 = 0; i2 < 21; i2++)
          acc[i2] += wgt * xs[cbase + ob[i2] + kyo];
      }
  }
  float bo = b[o];
  #pragma unroll
  for (int i2 = 0; i2 < 21; i2++) {
    int p = p0 + i2;
    if (p < p1) fm2[t * 5184 + o * 81 + p] = fmaxf(acc[i2] + bo, 0.f);
  }
}

// ---------------- conv3: [T,64,9,9] -> vecs [T,49,256], k3 s1 ----------------
__global__ __launch_bounds__(256) void conv3_k(const float* __restrict__ fm2, const float* __restrict__ w,
                                               const float* __restrict__ b, float* __restrict__ vecs) {
  __shared__ float xs[64 * 81];
  __shared__ float ws4[256][37];
  int t = blockIdx.x, tid = threadIdx.x;
  for (int i = tid; i < 64 * 81; i += 256) xs[i] = fm2[t * 5184 + i];
  float acc[49];
  #pragma unroll
  for (int i = 0; i < 49; i++) acc[i] = 0.f;
  for (int c0 = 0; c0 < 64; c0 += 4) {
    __syncthreads();
    for (int i = tid; i < 256 * 36; i += 256) {
      int oo = i / 36, j = i - oo * 36;
      ws4[oo][j] = w[oo * 576 + c0 * 9 + j];
    }
    __syncthreads();
    for (int cc = 0; cc < 4; cc++)
      for (int ky = 0; ky < 3; ky++)
        for (int kx = 0; kx < 3; kx++) {
          float wgt = ws4[tid][cc * 9 + ky * 3 + kx];
          const float* xp = &xs[(c0 + cc) * 81 + ky * 9 + kx];
          #pragma unroll
          for (int yy = 0; yy < 7; yy++)
            #pragma unroll
            for (int xx = 0; xx < 7; xx++)
              acc[yy * 7 + xx] += wgt * xp[yy * 9 + xx];
        }
  }
  float bo = b[tid];
  for (int i = 0; i < 49; i++)
    vecs[(t * 49 + i) * 256 + tid] = fmaxf(acc[i] + bo, 0.f);
}

// ---------------- A[t,i,:] = vecs[t,i,:] @ W1^T + b1 ----------------
__global__ __launch_bounds__(256) void aprep_k(const float* __restrict__ vecs, const float* __restrict__ w1t,
                                               const float* __restrict__ b1, float* __restrict__ A) {
  __shared__ float vs[49][256];
  int t = blockIdx.x, tid = threadIdx.x;
  for (int i = tid; i < 49 * 256; i += 256) vs[i >> 8][i & 255] = vecs[t * 12544 + i];
  __syncthreads();
  float acc[49];
  #pragma unroll
  for (int i = 0; i < 49; i++) acc[i] = 0.f;
  for (int k = 0; k < 256; k++) {
    float wgt = w1t[k * 256 + tid];
    #pragma unroll
    for (int i = 0; i < 49; i++) acc[i] += vs[i][k] * wgt;
  }
  float bb = b1[tid];
  for (int i = 0; i < 49; i++) A[(t * 49 + i) * 256 + tid] = acc[i] + bb;
}

// ---------------- init comm words ----------------
__global__ void init_comm(unsigned long long* comm) {
  int idx = blockIdx.x * 256 + threadIdx.x;
  if (idx < PG_WORDS)
    __hip_atomic_store(&comm[idx], 0ull, __ATOMIC_RELAXED, __HIP_MEMORY_SCOPE_AGENT);
}

__device__ __forceinline__ float tanh_fast(float x) {
  float e = __expf(2.f * x);
  return 1.f - 2.f * __builtin_amdgcn_rcpf(e + 1.f);
}
__device__ __forceinline__ float sigm_fast(float x) {
  return __builtin_amdgcn_rcpf(1.f + __expf(-x));
}

// ---------------- sequential scan: 8 WGs, ONE exchange per step ----------
__global__ __launch_bounds__(256, 1) void scan_k(
    const float* __restrict__ A, const float* __restrict__ vecs,
    const __bf16* __restrict__ w2b, const __bf16* __restrict__ wihb, const __bf16* __restrict__ whhb,
    const float* __restrict__ b2g, const float* __restrict__ bihg, const float* __restrict__ bhhg,
    const float* __restrict__ qw, const float* __restrict__ qb,
    unsigned long long* pgm, float* out) {
  const int w = blockIdx.x;     // worker 0..7; owns input dims Kw=[32w,32w+32)

  __shared__ __bf16 Ss[64][264];   // tanh(A+h), rows 49..63 stay 0   (33.8KB)
  __shared__ float  Wt[64][264];   // logits, then normalized weights (67.6KB)
  __shared__ float  cxp[8][32];    // ctx partial per row-group, own cols
  __shared__ float  hs[HID];       // full h (replicated)
  __shared__ __bf16 hbf[HID];
  __shared__ __bf16 ctxkw[32];     // own-col ctx partial, bf16
  __shared__ __bf16 hkw[32];       // own-col h, bf16
  __shared__ float  b2s[HID];
  __shared__ float  gb[1024];      // own partial gates pg_w (f32)

  const int tid  = threadIdx.x;
  const int lane = tid & 63;
  const int wv   = tid >> 6;        // wave 0..3 (= LSTM gate id for pg MFMA)
  const int quad = lane >> 4;
  const int l15  = lane & 15;
  const int q8   = tid >> 5;        // 0..7: row group (rows q8+8i)
  const int pcol = (tid & 31) * 8;  // staging: 8 contiguous cols
  const int l32  = tid & 31;        // softmax/ctx lane within 32-group

  for (int i = tid; i < 64 * 264; i += 256) (&Ss[0][0])[i] = (__bf16)0.f;
  b2s[tid] = b2g[tid];
  hs[tid] = 0.f;
  hbf[tid] = (__bf16)0.f;
  // full per-dim gate biases (thread tid owns h dim tid)
  float cbias[4];
  #pragma unroll
  for (int g = 0; g < 4; g++) cbias[g] = bihg[256 * g + tid] + bhhg[256 * g + tid];
  float creg = 0.f;  // replicated cell state, thread tid owns dim tid

  // ---- register-resident MFMA B-fragments ----
  v8bf BW2[4][8];  // full W2: wave wv owns logit cols wv*64 + ntl*16 + l15
  #pragma unroll
  for (int ntl = 0; ntl < 4; ntl++) {
    const int row = wv * 64 + ntl * 16 + l15;
    #pragma unroll
    for (int k = 0; k < 8; k++)
      BW2[ntl][k] = *(const v8bf*)(w2b + row * 256 + k * 32 + quad * 8);
  }
  // K-sliced LSTM weights: gate wv, ALL 256 out dims, input dims Kw only
  v8bf BIH[16], BHH[16];
  #pragma unroll
  for (int nt = 0; nt < 16; nt++) {
    const int row = 256 * wv + nt * 16 + l15;
    BIH[nt] = *(const v8bf*)(wihb + row * 256 + 32 * w + quad * 8);
    BHH[nt] = *(const v8bf*)(whhb + row * 256 + 32 * w + quad * 8);
  }
  __syncthreads();

  // ---- step-0 prefetch: A rows q8+8i (full 256 cols slice), vecs own cols ----
  float4 aa[8][2];
  float  vv[7];
  {
    #pragma unroll
    for (int i = 0; i < 8; i++) {
      int row = q8 + 8 * i; int rc = (row < NI) ? row : (NI - 1);
      const float* Ap = A + ((long)rc) * HID + pcol;
      aa[i][0] = *(const float4*)Ap;
      aa[i][1] = *(const float4*)(Ap + 4);
    }
    #pragma unroll
    for (int i = 0; i < 7; i++) {
      int row = q8 + 8 * i; int rc = (row < NI) ? row : (NI - 1);
      vv[i] = vecs[((long)rc) * HID + 32 * w + l32];
    }
  }

  for (int t = 0; t < T_FRAMES; t++) {
    const int tn = (t + 1 < T_FRAMES) ? (t + 1) : t;

    // ---- stage s = tanh(A + h) for my 8 rows (rows >= 49 stay zero) ----
    {
      const float* hp = &hs[pcol];
      const float h0 = hp[0], h1 = hp[1], h2 = hp[2], h3 = hp[3];
      const float h4 = hp[4], h5 = hp[5], h6 = hp[6], h7 = hp[7];
      #pragma unroll
      for (int i = 0; i < 8; i++) {
        int row = q8 + 8 * i;
        if (row < NI) {
          v8bf sv;
          sv[0] = (__bf16)tanh_fast(aa[i][0].x + h0);
          sv[1] = (__bf16)tanh_fast(aa[i][0].y + h1);
          sv[2] = (__bf16)tanh_fast(aa[i][0].z + h2);
          sv[3] = (__bf16)tanh_fast(aa[i][0].w + h3);
          sv[4] = (__bf16)tanh_fast(aa[i][1].x + h4);
          sv[5] = (__bf16)tanh_fast(aa[i][1].y + h5);
          sv[6] = (__bf16)tanh_fast(aa[i][1].z + h6);
          sv[7] = (__bf16)tanh_fast(aa[i][1].w + h7);
          *(v8bf*)&Ss[row][pcol] = sv;
        }
      }
    }
    __syncthreads();  // B1: Ss ready

    // prefetch next step's A (lands during logits/softmax/exchange)
    #pragma unroll
    for (int i = 0; i < 8; i++) {
      int row = q8 + 8 * i; int rc = (row < NI) ? row : (NI - 1);
      const float* Ap = A + ((long)tn * NI + rc) * HID + pcol;
      aa[i][0] = *(const float4*)Ap;
      aa[i][1] = *(const float4*)(Ap + 4);
    }

    // ---- logits = s @ W2^T + b2, ALL 49 rows (4 row-tiles x wave's 64 cols) ----
    #pragma unroll
    for (int rt = 0; rt < 4; rt++) {
      v4f acc[4];
      #pragma unroll
      for (int ntl = 0; ntl < 4; ntl++) acc[ntl] = (v4f){0.f, 0.f, 0.f, 0.f};
      #pragma unroll
      for (int k = 0; k < 8; k++) {
        const v8bf av = *(const v8bf*)&Ss[rt * 16 + l15][k * 32 + quad * 8];
        #pragma unroll
        for (int ntl = 0; ntl < 4; ntl++)
          acc[ntl] = __builtin_amdgcn_mfma_f32_16x16x32_bf16(av, BW2[ntl][k], acc[ntl], 0, 0, 0);
      }
      #pragma unroll
      for (int ntl = 0; ntl < 4; ntl++) {
        const int col = wv * 64 + ntl * 16 + l15;
        const float bb = b2s[col];
        #pragma unroll
        for (int reg = 0; reg < 4; reg++)
          Wt[rt * 16 + quad * 4 + reg][col] = acc[ntl][reg] + bb;
      }
    }
    __syncthreads();  // B2: Wt (logits) ready

    // ---- softmax per row (group q8 does rows q8+8i), stride-32 lane map ----
    #pragma unroll
    for (int i = 0; i < 7; i++) {
      int row = q8 + 8 * i;
      if (row < NI) {
        float x[8];
        #pragma unroll
        for (int j = 0; j < 8; j++) x[j] = Wt[row][l32 + 32 * j];
        float m = x[0];
        #pragma unroll
        for (int j = 1; j < 8; j++) m = fmaxf(m, x[j]);
        #pragma unroll
        for (int off = 16; off; off >>= 1) m = fmaxf(m, __shfl_xor(m, off, 64));
        float e[8], sm = 0.f;
        #pragma unroll
        for (int j = 0; j < 8; j++) { e[j] = __expf(x[j] - m); sm += e[j]; }
        #pragma unroll
        for (int off = 16; off; off >>= 1) sm += __shfl_xor(sm, off, 64);
        const float inv = __builtin_amdgcn_rcpf(sm);
        #pragma unroll
        for (int j = 0; j < 8; j++) Wt[row][l32 + 32 * j] = e[j] * inv;
      }
    }
    __syncthreads();  // B3: normalized weights in Wt

    // ---- ctx partial at my own 32 cols: sum over my rows of w * v ----
    {
      float cacc = 0.f;
      #pragma unroll
      for (int i = 0; i < 7; i++) {
        int row = q8 + 8 * i;
        if (row < NI) cacc += Wt[row][32 * w + l32] * vv[i];
      }
      cxp[q8][l32] = cacc;
    }
    // prefetch next step's vecs (own cols)
    #pragma unroll
    for (int i = 0; i < 7; i++) {
      int row = q8 + 8 * i; int rc = (row < NI) ? row : (NI - 1);
      vv[i] = vecs[((long)tn * NI + rc) * HID + 32 * w + l32];
    }
    __syncthreads();  // B4: cxp ready

    if (tid < 32) {
      float cp = 0.f;
      #pragma unroll
      for (int r = 0; r < 8; r++) cp += cxp[r][tid];
      ctxkw[tid] = (__bf16)cp;
      hkw[tid] = hbf[32 * w + tid];
    }
    __syncthreads();  // B5: ctxkw/hkw ready

    // ---- pg = ctx[Kw] @ Wih[:,Kw]^T + h[Kw] @ Whh[:,Kw]^T (K=32 MFMA) ----
    #pragma unroll
    for (int nt = 0; nt < 16; nt++) {
      v8bf cf, hf;
      #pragma unroll
      for (int z = 0; z < 8; z++) { cf[z] = (__bf16)0.f; hf[z] = (__bf16)0.f; }
      if (l15 == 0) {
        cf = *(const v8bf*)&ctxkw[quad * 8];
        hf = *(const v8bf*)&hkw[quad * 8];
      }
      v4f gacc = (v4f){0.f, 0.f, 0.f, 0.f};
      gacc = __builtin_amdgcn_mfma_f32_16x16x32_bf16(cf, BIH[nt], gacc, 0, 0, 0);
      gacc = __builtin_amdgcn_mfma_f32_16x16x32_bf16(hf, BHH[nt], gacc, 0, 0, 0);
      float tot = gacc[0] + gacc[1] + gacc[2] + gacc[3];
      tot += __shfl_xor(tot, 16, 64);
      tot += __shfl_xor(tot, 32, 64);
      if (lane < 16) gb[256 * wv + nt * 16 + lane] = tot;
    }
    __syncthreads();  // B6: gb (own pg) ready

    // ---- publish pg into buffer t&1 as (seq<<32 | f32bits), seq = t+1 ----
    {
      unsigned long long* dst = pgm + ((size_t)(t & 1) * NWG + w) * 1024;
      const unsigned long long sq = ((unsigned long long)(unsigned)(t + 1)) << 32;
      #pragma unroll
      for (int g = 0; g < 4; g++) {
        unsigned long long pk = sq | (unsigned long long)__float_as_uint(gb[256 * g + tid]);
        __hip_atomic_store(&dst[256 * g + tid], pk, __ATOMIC_RELAXED, __HIP_MEMORY_SCOPE_AGENT);
      }
    }

    // ---- gather remote pg (uniform poll-gather: detecting iter == data) ----
    float grem[7][4];
    {
      const unsigned ctgt = (unsigned)(t + 1);
      const unsigned long long* base = pgm + (size_t)(t & 1) * NWG * 1024;
      int gd = 0;
      while (true) {
        bool ok = true;
        #pragma unroll
        for (int pi = 0; pi < 7; pi++) {
          const int p = pi + (pi >= w ? 1 : 0);
          #pragma unroll
          for (int g = 0; g < 4; g++) {
            unsigned long long pk = __hip_atomic_load(&base[(size_t)p * 1024 + 256 * g + tid],
                                                      __ATOMIC_RELAXED, __HIP_MEMORY_SCOPE_AGENT);
            ok &= ((unsigned)(pk >> 32) == ctgt);
            grem[pi][g] = __uint_as_float((unsigned)pk);
          }
        }
        if (__all(ok) || ++gd > 5000000) break;
        __builtin_amdgcn_s_sleep(1);
      }
    }

    // ---- replicated cell update: thread tid owns dim tid ----
    {
      float gt[4];
      #pragma unroll
      for (int g = 0; g < 4; g++) {
        float s = gb[256 * g + tid];   // own partial (identical bits to published)
        #pragma unroll
        for (int pi = 0; pi < 7; pi++) s += grem[pi][g];
        gt[g] = s + cbias[g];
      }
      float si = sigm_fast(gt[0]);
      float sf = sigm_fast(gt[1]);
      float so = sigm_fast(gt[3]);
      creg = sf * creg + si * tanh_fast(gt[2]);
      float hn = so * tanh_fast(creg);
      hs[tid] = hn;
      hbf[tid] = (__bf16)hn;
    }
    __syncthreads();  // B7: h ready for next step (also fences gb reuse)
  }

  // q = h_T @ q_w^T + q_b  (h is fully local in every WG)
  if (w == 0 && tid < NA) {
    float acc = qb[tid];
    for (int k = 0; k < HID; k++) acc += hs[k] * qw[tid * HID + k];
    out[tid] = acc;
  }
}

extern "C" void kernel_launch(void* const* d_in, const int* in_sizes, int n_in,
                              void* d_out, int out_size, void* d_ws, size_t ws_size,
                              hipStream_t stream) {
  const float* frames = (const float*)d_in[0];
  const float* c1w = (const float*)d_in[1];
  const float* c1b = (const float*)d_in[2];
  const float* c2w = (const float*)d_in[3];
  const float* c2b = (const float*)d_in[4];
  const float* c3w = (const float*)d_in[5];
  const float* c3b = (const float*)d_in[6];
  const float* aw1 = (const float*)d_in[7];
  const float* ab1 = (const float*)d_in[8];
  const float* aw2 = (const float*)d_in[9];
  const float* ab2 = (const float*)d_in[10];
  const float* wih = (const float*)d_in[11];
  const float* whh = (const float*)d_in[12];
  const float* bih = (const float*)d_in[13];
  const float* bhh = (const float*)d_in[14];
  const float* qw  = (const float*)d_in[15];
  const float* qb  = (const float*)d_in[16];

  char* ws = (char*)d_ws;
  float*  fm1   = (float*)(ws + OFF_FM1);
  float*  A     = (float*)(ws + OFF_FM1);   // alias: fm1 dead after conv2
  float*  fm2   = (float*)(ws + OFF_FM2);
  float*  vecs  = (float*)(ws + OFF_VECS);
  __bf16* w2b   = (__bf16*)(ws + OFF_W2B);
  __bf16* wihb  = (__bf16*)(ws + OFF_WIHB);
  __bf16* whhb  = (__bf16*)(ws + OFF_WHHB);
  float*  w1t   = (float*)(ws + OFF_W1T);
  unsigned long long* pgm = (unsigned long long*)(ws + OFF_COMM);  // aliases fm2

  prep_weights<<<256, 256, 0, stream>>>(aw2, wih, whh, aw1, w2b, wihb, whhb, w1t);
  conv1_k<<<102400, 256, 0, stream>>>(frames, c1w, c1b, fm1);
  conv2_k<<<T_FRAMES, 256, 0, stream>>>(fm1, c2w, c2b, fm2);
  conv3_k<<<T_FRAMES, 256, 0, stream>>>(fm2, c3w, c3b, vecs);
  aprep_k<<<T_FRAMES, 256, 0, stream>>>(vecs, w1t, ab1, A);
  init_comm<<<64, 256, 0, stream>>>(pgm);  // after conv3: pgm aliases fm2
  scan_k<<<NWG, 256, 0, stream>>>(A, vecs, w2b, wihb, whhb, ab2, bih, bhh, qw, qb,
                                  pgm, (float*)d_out);
}

// Round 10
// 14133.549 us; speedup vs baseline: 2.1724x; 2.1724x over previous
//
#include <hip/hip_runtime.h>
#include <hip/hip_bf16.h>
#include <math.h>

// DARQN: conv×3 -> per-step additive attention + LSTM scan (T=2048) -> q head.
// R13: MEGA-KERNEL — scan (blocks 0..7, R4-byte-identical comm) runs
// CONCURRENTLY with per-frame conv producers (blocks 8..2055).
//  - transport experiments exhausted (R5/R6/R8/R11 null-or-worse, R7/R12
//    replication worse): R4's 2-leg ~2.6us/leg is intrinsic. The recoverable
//    time is the 1.84ms serial prologue, hidden under the scan's idle latency.
//  - producer block = 1 frame: conv1->conv2->conv3->aprep entirely in LDS
//    (117KB carved, bit-identical order to the proven kernels); writes only
//    vecs[t], A[t] to global; release-publishes flags[t].
//  - scan watermark: every 64 steps, all waves poll flags[t..t+63] (relaxed,
//    s_sleep-paced), then ONE acquire load fences; ~0.005us/step amortized.
//  - deadlock-free: producers wait on nothing; scan waits only on flags set
//    by independent blocks. Guards break visibly, never hang.

#define T_FRAMES 2048
#define NI 49
#define HID 256
#define NA 18
#define NWG 8

typedef __bf16 v8bf __attribute__((ext_vector_type(8)));
typedef float v4f __attribute__((ext_vector_type(4)));

// ---------------- workspace layout (bytes) ----------------
static constexpr size_t OFF_FM1   = 0;                  // A [2048,49,256] f32 (fm1 never hits global now)
static constexpr size_t OFF_FM2   = 104857600;          // comm block (fm2 never hits global now)
static constexpr size_t OFF_VECS  = 147324928;          // vecs [2048,49,256] f32
static constexpr size_t OFF_W2B   = 250085376;          // bf16 256*256
static constexpr size_t OFF_WIHB  = OFF_W2B  + 131072;  // bf16 1024*256
static constexpr size_t OFF_WHHB  = OFF_WIHB + 524288;  // bf16 1024*256
static constexpr size_t OFF_W1T   = OFF_WHHB + 524288;  // f32 256*256
// comm: hbuf u64[256] | cpub u64[8*128] | flags u64[2048]
static constexpr size_t OFF_COMM  = OFF_FM2;
static constexpr int COMM_WORDS = 256 + NWG * 128 + T_FRAMES;  // 3328

// ---------------- weight prep ----------------
__global__ void prep_weights(const float* __restrict__ w2, const float* __restrict__ wih,
                             const float* __restrict__ whh, const float* __restrict__ w1,
                             __bf16* w2b, __bf16* wihb, __bf16* whhb, float* w1t) {
  int idx = blockIdx.x * 256 + threadIdx.x;
  int stride = gridDim.x * 256;
  for (int i = idx; i < 65536; i += stride) w2b[i] = (__bf16)w2[i];
  for (int i = idx; i < 262144; i += stride) wihb[i] = (__bf16)wih[i];
  for (int i = idx; i < 262144; i += stride) whhb[i] = (__bf16)whh[i];
  for (int i = idx; i < 65536; i += stride) {
    int r = i >> 8, c = i & 255;
    w1t[c * 256 + r] = w1[i];
  }
}

// ---------------- init comm words ----------------
__global__ void init_comm(unsigned long long* comm) {
  int idx = blockIdx.x * 256 + threadIdx.x;
  if (idx < COMM_WORDS)
    __hip_atomic_store(&comm[idx], 0ull, __ATOMIC_RELAXED, __HIP_MEMORY_SCOPE_AGENT);
}

__device__ __forceinline__ float tanh_fast(float x) {
  float e = __expf(2.f * x);
  return 1.f - 2.f * __builtin_amdgcn_rcpf(e + 1.f);
}
__device__ __forceinline__ float sigm_fast(float x) {
  return __builtin_amdgcn_rcpf(1.f + __expf(-x));
}

// ---------------- mega-kernel: scan (blocks 0..7) + producers (8..2055) ----
__global__ __launch_bounds__(256, 1) void mega_k(
    const float* frames,
    const float* __restrict__ c1w, const float* __restrict__ c1b,
    const float* __restrict__ c2w, const float* __restrict__ c2b,
    const float* __restrict__ c3w, const float* __restrict__ c3b,
    const float* __restrict__ w1t, const float* __restrict__ ab1,
    float* A, float* vecs,
    const __bf16* __restrict__ w2b, const __bf16* __restrict__ wihb,
    const __bf16* __restrict__ whhb,
    const float* __restrict__ b2g, const float* __restrict__ bihg,
    const float* __restrict__ bhhg,
    const float* __restrict__ qw, const float* __restrict__ qb,
    unsigned long long* hbuf, unsigned long long* cpub, unsigned long long* flags,
    float* out) {
  // ---- scan statics (28.4KB) ----
  __shared__ __bf16 Ss[16][264];
  __shared__ float hs[HID];
  __shared__ __bf16 hbf[HID];
  __shared__ float Wt[8][HID];
  __shared__ float cxp[8][HID];
  __shared__ float b2s[HID];
  __shared__ float gb[4][32];
  __shared__ unsigned cpl[128];
  // ---- producer scratch (117.5KB), carved with stage-overlap ----
  //   [0,7104): xin (7056 f32)      -> later fm2s (5184 f32)
  //   [7104,19904): fm1s (12800)    -> later vecs_s (12544)
  //   [19904,29376): ws4p (256*37)
  __shared__ __attribute__((aligned(16))) float pbuf_f[29376];

  const int tid = threadIdx.x;

  if (blockIdx.x >= 8) {
    // ================= PRODUCER: one frame, conv1->conv2->conv3->aprep ====
    const int f = (int)blockIdx.x - 8;
    float* xin    = pbuf_f;
    float* fm1s   = pbuf_f + 7104;
    float* ws4p   = pbuf_f + 19904;
    float* fm2s   = xin;    // alias: xin dead after conv1
    float* vecs_s = fm1s;   // alias: fm1 dead after conv2

    // conv1: [1,84,84] -> [32,20,20], k8 s4 (bit-identical to conv1_k)
    for (int i = tid; i < 7056; i += 256) xin[i] = frames[(long)f * 7056 + i];
    __syncthreads();
    for (int i = tid; i < 12800; i += 256) {
      int xx = i % 20, yy = (i / 20) % 20, o = i / 400;
      const float* xp = xin + yy * 4 * 84 + xx * 4;
      const float* wp = c1w + o * 64;
      float acc = c1b[o];
      #pragma unroll
      for (int ky = 0; ky < 8; ky++)
        #pragma unroll
        for (int kx = 0; kx < 8; kx++)
          acc += xp[ky * 84 + kx] * wp[ky * 8 + kx];
      fm1s[i] = fmaxf(acc, 0.f);
    }
    __syncthreads();

    // conv2: [32,20,20] -> [64,9,9], k4 s2 (bit-identical to conv2_k)
    {
      int o = tid >> 2, q = tid & 3;
      int p0 = q * 21, p1 = (p0 + 21 < 81) ? p0 + 21 : 81;
      int ob[21];
      #pragma unroll
      for (int i2 = 0; i2 < 21; i2++) {
        int p = p0 + i2; if (p > 80) p = 80;
        int yy = p / 9, xx2 = p - yy * 9;
        ob[i2] = yy * 40 + xx2 * 2;
      }
      float acc[21];
      #pragma unroll
      for (int i2 = 0; i2 < 21; i2++) acc[i2] = 0.f;
      for (int c = 0; c < 32; c++) {
        int cbase = c * 400;
        for (int ky = 0; ky < 4; ky++)
          for (int kx = 0; kx < 4; kx++) {
            float wgt = c2w[((o * 32 + c) * 4 + ky) * 4 + kx];
            int kyo = ky * 20 + kx;
            #pragma unroll
            for (int i2 = 0; i2 < 21; i2++)
              acc[i2] += wgt * fm1s[cbase + ob[i2] + kyo];
          }
      }
      float bo = c2b[o];
      #pragma unroll
      for (int i2 = 0; i2 < 21; i2++) {
        int p = p0 + i2;
        if (p < p1) fm2s[o * 81 + p] = fmaxf(acc[i2] + bo, 0.f);
      }
    }

    // conv3: [64,9,9] -> [49,256] (bit-identical to conv3_k)
    {
      float acc[49];
      #pragma unroll
      for (int i = 0; i < 49; i++) acc[i] = 0.f;
      for (int c0 = 0; c0 < 64; c0 += 4) {
        __syncthreads();   // first iter also fences conv2's fm2s writes
        for (int i = tid; i < 256 * 36; i += 256) {
          int oo = i / 36, j = i - oo * 36;
          ws4p[oo * 37 + j] = c3w[oo * 576 + c0 * 9 + j];
        }
        __syncthreads();
        for (int cc = 0; cc < 4; cc++)
          for (int ky = 0; ky < 3; ky++)
            for (int kx = 0; kx < 3; kx++) {
              float wgt = ws4p[tid * 37 + cc * 9 + ky * 3 + kx];
              const float* xp = &fm2s[(c0 + cc) * 81 + ky * 9 + kx];
              #pragma unroll
              for (int yy = 0; yy < 7; yy++)
                #pragma unroll
                for (int xx = 0; xx < 7; xx++)
                  acc[yy * 7 + xx] += wgt * xp[yy * 9 + xx];
            }
      }
      float bo = c3b[tid];
      for (int i = 0; i < 49; i++) {
        float v = fmaxf(acc[i] + bo, 0.f);
        vecs[((long)f * 49 + i) * 256 + tid] = v;
        vecs_s[i * 256 + tid] = v;   // fm1 region (dead since conv2)
      }
    }
    __syncthreads();

    // aprep: A = vecs @ W1^T + b1 (bit-identical to aprep_k)
    {
      float acc2[49];
      #pragma unroll
      for (int i = 0; i < 49; i++) acc2[i] = 0.f;
      for (int k = 0; k < 256; k++) {
        float wgt = w1t[k * 256 + tid];
        #pragma unroll
        for (int i = 0; i < 49; i++) acc2[i] += vecs_s[i * 256 + k] * wgt;
      }
      float bb = ab1[tid];
      for (int i = 0; i < 49; i++)
        A[((long)f * 49 + i) * 256 + tid] = acc2[i] + bb;
    }
    __syncthreads();  // compiler drains vmcnt before barrier: all stores done
    if (tid == 0)
      __hip_atomic_store(&flags[f], (unsigned long long)(f + 1),
                         __ATOMIC_RELEASE, __HIP_MEMORY_SCOPE_AGENT);
    return;
  }

  // ================= SCAN: R4 body + flag watermark ========================
  const int w = (int)blockIdx.x;    // worker 0..7
  const int lane = tid & 63;
  const int wv = tid >> 6;          // wave 0..3 (= LSTM gate id)
  const int quad = lane >> 4;
  const int l15 = lane & 15;
  const int r0 = 6 * w;                       // attention rows [r0, r0+nr)
  const int nr = (w < 7) ? 6 : 7;             // 7*6 + 7 = 49
  const int prow = tid >> 5;        // 0..7: staging row
  const int pcol = (tid & 31) * 8;  // 8 contiguous cols

  for (int i = tid; i < 16 * 264; i += 256) (&Ss[0][0])[i] = (__bf16)0.f;
  for (int i = tid; i < 8 * HID; i += 256) (&cxp[0][0])[i] = 0.f;
  b2s[tid] = b2g[tid];
  hs[tid] = 0.f;
  hbf[tid] = (__bf16)0.f;
  float cbias[4];
  if (tid < 32) {
    #pragma unroll
    for (int g = 0; g < 4; g++) {
      int row = 256 * g + 32 * w + tid;
      cbias[g] = bihg[row] + bhhg[row];
    }
  }
  float creg = 0.f;  // cell state, tid<32 owns dim 32*w+tid

  // ---- register-resident MFMA B-fragments ----
  v8bf BW2[4][8];
  #pragma unroll
  for (int ntl = 0; ntl < 4; ntl++) {
    const int row = wv * 64 + ntl * 16 + l15;
    #pragma unroll
    for (int k = 0; k < 8; k++)
      BW2[ntl][k] = *(const v8bf*)(w2b + row * 256 + k * 32 + quad * 8);
  }
  v8bf BIH[2][8], BHH[2][8];
  #pragma unroll
  for (int nt = 0; nt < 2; nt++) {
    const int row = 256 * wv + 32 * w + nt * 16 + l15;
    #pragma unroll
    for (int k = 0; k < 8; k++) {
      BIH[nt][k] = *(const v8bf*)(wihb + row * 256 + k * 32 + quad * 8);
      BHH[nt][k] = *(const v8bf*)(whhb + row * 256 + k * 32 + quad * 8);
    }
  }
  __syncthreads();

  int ready = 0;  // frames confirmed produced

  for (int t = 0; t < T_FRAMES; t++) {
    // ---- watermark: confirm frames [t, t+64) produced (once per 64 steps) --
    if (t >= ready) {
      int idx = t + lane; if (idx > T_FRAMES - 1) idx = T_FRAMES - 1;
      const unsigned long long want = (unsigned long long)(idx + 1);
      unsigned long long fv =
          __hip_atomic_load(&flags[idx], __ATOMIC_RELAXED, __HIP_MEMORY_SCOPE_AGENT);
      int gd = 0;
      while (!__all(fv == want) && ++gd < 5000000) {
        __builtin_amdgcn_s_sleep(8);
        fv = __hip_atomic_load(&flags[idx], __ATOMIC_RELAXED, __HIP_MEMORY_SCOPE_AGENT);
      }
      // one acquire load fences: released producer data (in IF$) becomes
      // visible; also a compiler barrier against hoisting A/vecs loads.
      (void)__hip_atomic_load(&flags[idx], __ATOMIC_ACQUIRE, __HIP_MEMORY_SCOPE_AGENT);
      ready = t + 64;
    }

    // issue this step's A/vecs loads (fly during the h wait)
    int rr = r0 + prow; if (rr > 48) rr = 48;
    const float* Ap = A + ((long)t * NI + rr) * HID + pcol;
    const float* Vp = vecs + ((long)t * NI + rr) * HID + pcol;
    const float4 a40 = *(const float4*)(Ap);
    const float4 a41 = *(const float4*)(Ap + 4);
    const float4 v40 = *(const float4*)(Vp);
    const float4 v41 = *(const float4*)(Vp + 4);

    if (t > 0) {  // per-thread poll of own h word: (seq<<32)|f32bits
      const unsigned tgt = (unsigned)t;
      unsigned long long pk =
          __hip_atomic_load(&hbuf[tid], __ATOMIC_RELAXED, __HIP_MEMORY_SCOPE_AGENT);
      int gd = 0;
      while ((unsigned)(pk >> 32) < tgt && ++gd < 5000000) {
        __builtin_amdgcn_s_sleep(1);
        pk = __hip_atomic_load(&hbuf[tid], __ATOMIC_RELAXED, __HIP_MEMORY_SCOPE_AGENT);
      }
      float hv = __uint_as_float((unsigned)pk);
      hs[tid] = hv;
      hbf[tid] = (__bf16)hv;
      __syncthreads();  // B1
    }

    // stage s = tanh(A + h) as bf16 (rows >= nr stay zero)
    if (prow < nr) {
      const float* hp = &hs[pcol];
      v8bf sv;
      sv[0] = (__bf16)tanh_fast(a40.x + hp[0]);
      sv[1] = (__bf16)tanh_fast(a40.y + hp[1]);
      sv[2] = (__bf16)tanh_fast(a40.z + hp[2]);
      sv[3] = (__bf16)tanh_fast(a40.w + hp[3]);
      sv[4] = (__bf16)tanh_fast(a41.x + hp[4]);
      sv[5] = (__bf16)tanh_fast(a41.y + hp[5]);
      sv[6] = (__bf16)tanh_fast(a41.z + hp[6]);
      sv[7] = (__bf16)tanh_fast(a41.w + hp[7]);
      *(v8bf*)&Ss[prow][pcol] = sv;
    }
    __syncthreads();  // B2

    // logits = s @ W2^T + b2 (rows 0..7 valid)
    v4f acc[4];
    #pragma unroll
    for (int ntl = 0; ntl < 4; ntl++) acc[ntl] = (v4f){0.f, 0.f, 0.f, 0.f};
    #pragma unroll
    for (int k = 0; k < 8; k++) {
      const v8bf av = *(const v8bf*)&Ss[l15][k * 32 + quad * 8];
      #pragma unroll
      for (int ntl = 0; ntl < 4; ntl++)
        acc[ntl] = __builtin_amdgcn_mfma_f32_16x16x32_bf16(av, BW2[ntl][k], acc[ntl], 0, 0, 0);
    }
    if (quad < 2) {
      #pragma unroll
      for (int ntl = 0; ntl < 4; ntl++) {
        const int col = wv * 64 + ntl * 16 + l15;
        const float bb = b2s[col];
        #pragma unroll
        for (int reg = 0; reg < 4; reg++)
          Wt[quad * 4 + reg][col] = acc[ntl][reg] + bb;
      }
    }
    __syncthreads();  // B3

    // softmax + ctx products (invalid rows stay zero)
    if (prow < nr) {
      float x[8];
      *(float4*)&x[0] = *(const float4*)&Wt[prow][pcol];
      *(float4*)&x[4] = *(const float4*)&Wt[prow][pcol + 4];
      float m = x[0];
      #pragma unroll
      for (int i = 1; i < 8; i++) m = fmaxf(m, x[i]);
      #pragma unroll
      for (int off = 16; off; off >>= 1) m = fmaxf(m, __shfl_xor(m, off, 64));
      float e[8], sm = 0.f;
      #pragma unroll
      for (int i = 0; i < 8; i++) { e[i] = __expf(x[i] - m); sm += e[i]; }
      #pragma unroll
      for (int off = 16; off; off >>= 1) sm += __shfl_xor(sm, off, 64);
      const float inv = __builtin_amdgcn_rcpf(sm);
      cxp[prow][pcol + 0] = e[0] * inv * v40.x;
      cxp[prow][pcol + 1] = e[1] * inv * v40.y;
      cxp[prow][pcol + 2] = e[2] * inv * v40.z;
      cxp[prow][pcol + 3] = e[3] * inv * v40.w;
      cxp[prow][pcol + 4] = e[4] * inv * v41.x;
      cxp[prow][pcol + 5] = e[5] * inv * v41.y;
      cxp[prow][pcol + 6] = e[6] * inv * v41.z;
      cxp[prow][pcol + 7] = e[7] * inv * v41.w;
    }
    __syncthreads();  // B5

    // channel sum -> bf16 pack -> publish u64 (seq | 2×bf16)
    float cp = 0.f;
    #pragma unroll
    for (int r = 0; r < 8; r++) cp += cxp[r][tid];
    float cpo = __shfl_xor(cp, 1, 64);
    if ((tid & 1) == 0) {
      union { __bf16 b; unsigned short s; } lo, hi;
      lo.b = (__bf16)cp; hi.b = (__bf16)cpo;
      unsigned word = ((unsigned)hi.s << 16) | (unsigned)lo.s;
      unsigned long long pk =
          ((unsigned long long)(unsigned)(t + 1) << 32) | (unsigned long long)word;
      __hip_atomic_store(&cpub[w * 128 + (tid >> 1)], pk, __ATOMIC_RELAXED, __HIP_MEMORY_SCOPE_AGENT);
      cpl[tid >> 1] = word;
    }
    __syncthreads();  // B6

    // h @ Whh^T chain — runs while remote publishes land
    v4f gacc[2];
    gacc[0] = (v4f){0.f, 0.f, 0.f, 0.f};
    gacc[1] = (v4f){0.f, 0.f, 0.f, 0.f};
    #pragma unroll
    for (int k = 0; k < 8; k++) {
      v8bf hf;
      #pragma unroll
      for (int z = 0; z < 8; z++) hf[z] = (__bf16)0.f;
      if (l15 == 0) hf = *(const v8bf*)&hbf[k * 32 + quad * 8];
      gacc[0] = __builtin_amdgcn_mfma_f32_16x16x32_bf16(hf, BHH[0][k], gacc[0], 0, 0, 0);
      gacc[1] = __builtin_amdgcn_mfma_f32_16x16x32_bf16(hf, BHH[1][k], gacc[1], 0, 0, 0);
    }

    // uniform poll-gather of remote ctx partials (last iteration == the data)
    unsigned long long g[8][4];
    const unsigned ctgt = (unsigned)(t + 1);
    const bool remote = (l15 < NWG) && (l15 != w);
    {
      int gd = 0;
      while (true) {
        bool ok = true;
        if (remote) {
          const unsigned long long* src = cpub + l15 * 128 + quad * 4;
          #pragma unroll
          for (int k = 0; k < 8; k++)
            #pragma unroll
            for (int q2 = 0; q2 < 4; q2++) {
              g[k][q2] = __hip_atomic_load(&src[k * 16 + q2], __ATOMIC_RELAXED, __HIP_MEMORY_SCOPE_AGENT);
              ok &= ((unsigned)(g[k][q2] >> 32) >= ctgt);
            }
        }
        if (__all(ok) || ++gd > 5000000) break;
        __builtin_amdgcn_s_sleep(1);
      }
    }

    // P rows as MFMA A-frags; accumulate
    #pragma unroll
    for (int k = 0; k < 8; k++) {
      union { unsigned u[4]; v8bf v; } pf;
      if (remote) {
        pf.u[0] = (unsigned)g[k][0]; pf.u[1] = (unsigned)g[k][1];
        pf.u[2] = (unsigned)g[k][2]; pf.u[3] = (unsigned)g[k][3];
      } else if (l15 == w) {
        pf.u[0] = cpl[k * 16 + quad * 4 + 0];
        pf.u[1] = cpl[k * 16 + quad * 4 + 1];
        pf.u[2] = cpl[k * 16 + quad * 4 + 2];
        pf.u[3] = cpl[k * 16 + quad * 4 + 3];
      } else {
        pf.u[0] = pf.u[1] = pf.u[2] = pf.u[3] = 0u;
      }
      gacc[0] = __builtin_amdgcn_mfma_f32_16x16x32_bf16(pf.v, BIH[0][k], gacc[0], 0, 0, 0);
      gacc[1] = __builtin_amdgcn_mfma_f32_16x16x32_bf16(pf.v, BIH[1][k], gacc[1], 0, 0, 0);
    }
    #pragma unroll
    for (int nt = 0; nt < 2; nt++) {
      float tot = gacc[nt][0] + gacc[nt][1] + gacc[nt][2] + gacc[nt][3];
      tot += __shfl_xor(tot, 16, 64);
      tot += __shfl_xor(tot, 32, 64);
      if (lane < 16) gb[wv][nt * 16 + lane] = tot;
    }
    __syncthreads();  // B7

    // cell update; publish h slice as (seq | f32bits)
    if (tid < 32) {
      float gi = gb[0][tid] + cbias[0];
      float gf = gb[1][tid] + cbias[1];
      float gg = gb[2][tid] + cbias[2];
      float go = gb[3][tid] + cbias[3];
      float si = sigm_fast(gi);
      float sf = sigm_fast(gf);
      float so = sigm_fast(go);
      creg = sf * creg + si * tanh_fast(gg);
      float hn = so * tanh_fast(creg);
      unsigned long long pk = ((unsigned long long)(unsigned)(t + 1) << 32) |
                              (unsigned long long)__float_as_uint(hn);
      __hip_atomic_store(&hbuf[32 * w + tid], pk, __ATOMIC_RELAXED, __HIP_MEMORY_SCOPE_AGENT);
    }
  }

  // q = h_T @ q_w^T + q_b
  if (w == 0) {
    const unsigned tgt = (unsigned)T_FRAMES;
    unsigned long long pk =
        __hip_atomic_load(&hbuf[tid], __ATOMIC_RELAXED, __HIP_MEMORY_SCOPE_AGENT);
    int gd = 0;
    while ((unsigned)(pk >> 32) < tgt && ++gd < 5000000) {
      __builtin_amdgcn_s_sleep(1);
      pk = __hip_atomic_load(&hbuf[tid], __ATOMIC_RELAXED, __HIP_MEMORY_SCOPE_AGENT);
    }
    hs[tid] = __uint_as_float((unsigned)pk);
    __syncthreads();
    if (tid < NA) {
      float acc = qb[tid];
      for (int k = 0; k < HID; k++) acc += hs[k] * qw[tid * HID + k];
      out[tid] = acc;
    }
  }
}

extern "C" void kernel_launch(void* const* d_in, const int* in_sizes, int n_in,
                              void* d_out, int out_size, void* d_ws, size_t ws_size,
                              hipStream_t stream) {
  const float* frames = (const float*)d_in[0];
  const float* c1w = (const float*)d_in[1];
  const float* c1b = (const float*)d_in[2];
  const float* c2w = (const float*)d_in[3];
  const float* c2b = (const float*)d_in[4];
  const float* c3w = (const float*)d_in[5];
  const float* c3b = (const float*)d_in[6];
  const float* aw1 = (const float*)d_in[7];
  const float* ab1 = (const float*)d_in[8];
  const float* aw2 = (const float*)d_in[9];
  const float* ab2 = (const float*)d_in[10];
  const float* wih = (const float*)d_in[11];
  const float* whh = (const float*)d_in[12];
  const float* bih = (const float*)d_in[13];
  const float* bhh = (const float*)d_in[14];
  const float* qw  = (const float*)d_in[15];
  const float* qb  = (const float*)d_in[16];

  char* ws = (char*)d_ws;
  float*  A     = (float*)(ws + OFF_FM1);
  float*  vecs  = (float*)(ws + OFF_VECS);
  __bf16* w2b   = (__bf16*)(ws + OFF_W2B);
  __bf16* wihb  = (__bf16*)(ws + OFF_WIHB);
  __bf16* whhb  = (__bf16*)(ws + OFF_WHHB);
  float*  w1t   = (float*)(ws + OFF_W1T);
  unsigned long long* comm = (unsigned long long*)(ws + OFF_COMM);
  unsigned long long* hbuf  = comm;
  unsigned long long* cpub  = comm + 256;
  unsigned long long* flags = comm + 1280;

  prep_weights<<<256, 256, 0, stream>>>(aw2, wih, whh, aw1, w2b, wihb, whhb, w1t);
  init_comm<<<13, 256, 0, stream>>>(comm);
  mega_k<<<8 + T_FRAMES, 256, 0, stream>>>(
      frames, c1w, c1b, c2w, c2b, c3w, c3b, w1t, ab1,
      A, vecs, w2b, wihb, whhb, ab2, bih, bhh, qw, qb,
      hbuf, cpub, flags, (float*)d_out);
}

// Round 11
// 13939.352 us; speedup vs baseline: 2.2027x; 1.0139x over previous
//
#include <hip/hip_runtime.h>
#include <hip/hip_bf16.h>
#include <math.h>

// DARQN: conv×3 -> per-step additive attention + LSTM scan (T=2048) -> q head.
// R14: R13 mega-kernel (WIN: 14.13ms) + critical-path polish.
//  - column-major staging: thread tid stages column tid of its WG's rows,
//    needing only its OWN polled h word (register) -> barrier B1 and the
//    hs[] LDS round-trip are DELETED from the step loop. Same element set,
//    same float math -> absmax bit-identical.
//  - init_comm folded into prep_weights (one fewer serial dispatch).
//  - everything else byte-identical to R13 (producers, watermark, R4 comm).

#define T_FRAMES 2048
#define NI 49
#define HID 256
#define NA 18
#define NWG 8

typedef __bf16 v8bf __attribute__((ext_vector_type(8)));
typedef float v4f __attribute__((ext_vector_type(4)));

// ---------------- workspace layout (bytes) ----------------
static constexpr size_t OFF_FM1   = 0;                  // A [2048,49,256] f32
static constexpr size_t OFF_FM2   = 104857600;          // comm block
static constexpr size_t OFF_VECS  = 147324928;          // vecs [2048,49,256] f32
static constexpr size_t OFF_W2B   = 250085376;          // bf16 256*256
static constexpr size_t OFF_WIHB  = OFF_W2B  + 131072;  // bf16 1024*256
static constexpr size_t OFF_WHHB  = OFF_WIHB + 524288;  // bf16 1024*256
static constexpr size_t OFF_W1T   = OFF_WHHB + 524288;  // f32 256*256
// comm: hbuf u64[256] | cpub u64[8*128] | flags u64[2048]
static constexpr size_t OFF_COMM  = OFF_FM2;
static constexpr int COMM_WORDS = 256 + NWG * 128 + T_FRAMES;  // 3328

// ---------------- weight prep + comm init ----------------
__global__ void prep_weights(const float* __restrict__ w2, const float* __restrict__ wih,
                             const float* __restrict__ whh, const float* __restrict__ w1,
                             __bf16* w2b, __bf16* wihb, __bf16* whhb, float* w1t,
                             unsigned long long* comm) {
  int idx = blockIdx.x * 256 + threadIdx.x;
  int stride = gridDim.x * 256;
  for (int i = idx; i < 65536; i += stride) w2b[i] = (__bf16)w2[i];
  for (int i = idx; i < 262144; i += stride) wihb[i] = (__bf16)wih[i];
  for (int i = idx; i < 262144; i += stride) whhb[i] = (__bf16)whh[i];
  for (int i = idx; i < 65536; i += stride) {
    int r = i >> 8, c = i & 255;
    w1t[c * 256 + r] = w1[i];
  }
  for (int i = idx; i < COMM_WORDS; i += stride)
    __hip_atomic_store(&comm[i], 0ull, __ATOMIC_RELAXED, __HIP_MEMORY_SCOPE_AGENT);
}

__device__ __forceinline__ float tanh_fast(float x) {
  float e = __expf(2.f * x);
  return 1.f - 2.f * __builtin_amdgcn_rcpf(e + 1.f);
}
__device__ __forceinline__ float sigm_fast(float x) {
  return __builtin_amdgcn_rcpf(1.f + __expf(-x));
}

// ---------------- mega-kernel: scan (blocks 0..7) + producers (8..2055) ----
__global__ __launch_bounds__(256, 1) void mega_k(
    const float* frames,
    const float* __restrict__ c1w, const float* __restrict__ c1b,
    const float* __restrict__ c2w, const float* __restrict__ c2b,
    const float* __restrict__ c3w, const float* __restrict__ c3b,
    const float* __restrict__ w1t, const float* __restrict__ ab1,
    float* A, float* vecs,
    const __bf16* __restrict__ w2b, const __bf16* __restrict__ wihb,
    const __bf16* __restrict__ whhb,
    const float* __restrict__ b2g, const float* __restrict__ bihg,
    const float* __restrict__ bhhg,
    const float* __restrict__ qw, const float* __restrict__ qb,
    unsigned long long* hbuf, unsigned long long* cpub, unsigned long long* flags,
    float* out) {
  // ---- scan statics ----
  __shared__ __bf16 Ss[16][264];
  __shared__ float hs[HID];        // q-head only (not in step loop)
  __shared__ __bf16 hbf[HID];
  __shared__ float Wt[8][HID];
  __shared__ float cxp[8][HID];
  __shared__ float b2s[HID];
  __shared__ float gb[4][32];
  __shared__ unsigned cpl[128];
  // ---- producer scratch (117.5KB), carved with stage-overlap ----
  //   [0,7104): xin (7056 f32)      -> later fm2s (5184 f32)
  //   [7104,19904): fm1s (12800)    -> later vecs_s (12544)
  //   [19904,29376): ws4p (256*37)
  __shared__ __attribute__((aligned(16))) float pbuf_f[29376];

  const int tid = threadIdx.x;

  if (blockIdx.x >= 8) {
    // ================= PRODUCER: one frame, conv1->conv2->conv3->aprep ====
    const int f = (int)blockIdx.x - 8;
    float* xin    = pbuf_f;
    float* fm1s   = pbuf_f + 7104;
    float* ws4p   = pbuf_f + 19904;
    float* fm2s   = xin;    // alias: xin dead after conv1
    float* vecs_s = fm1s;   // alias: fm1 dead after conv2

    // conv1: [1,84,84] -> [32,20,20], k8 s4
    for (int i = tid; i < 7056; i += 256) xin[i] = frames[(long)f * 7056 + i];
    __syncthreads();
    for (int i = tid; i < 12800; i += 256) {
      int xx = i % 20, yy = (i / 20) % 20, o = i / 400;
      const float* xp = xin + yy * 4 * 84 + xx * 4;
      const float* wp = c1w + o * 64;
      float acc = c1b[o];
      #pragma unroll
      for (int ky = 0; ky < 8; ky++)
        #pragma unroll
        for (int kx = 0; kx < 8; kx++)
          acc += xp[ky * 84 + kx] * wp[ky * 8 + kx];
      fm1s[i] = fmaxf(acc, 0.f);
    }
    __syncthreads();

    // conv2: [32,20,20] -> [64,9,9], k4 s2
    {
      int o = tid >> 2, q = tid & 3;
      int p0 = q * 21, p1 = (p0 + 21 < 81) ? p0 + 21 : 81;
      int ob[21];
      #pragma unroll
      for (int i2 = 0; i2 < 21; i2++) {
        int p = p0 + i2; if (p > 80) p = 80;
        int yy = p / 9, xx2 = p - yy * 9;
        ob[i2] = yy * 40 + xx2 * 2;
      }
      float acc[21];
      #pragma unroll
      for (int i2 = 0; i2 < 21; i2++) acc[i2] = 0.f;
      for (int c = 0; c < 32; c++) {
        int cbase = c * 400;
        for (int ky = 0; ky < 4; ky++)
          for (int kx = 0; kx < 4; kx++) {
            float wgt = c2w[((o * 32 + c) * 4 + ky) * 4 + kx];
            int kyo = ky * 20 + kx;
            #pragma unroll
            for (int i2 = 0; i2 < 21; i2++)
              acc[i2] += wgt * fm1s[cbase + ob[i2] + kyo];
          }
      }
      float bo = c2b[o];
      #pragma unroll
      for (int i2 = 0; i2 < 21; i2++) {
        int p = p0 + i2;
        if (p < p1) fm2s[o * 81 + p] = fmaxf(acc[i2] + bo, 0.f);
      }
    }

    // conv3: [64,9,9] -> [49,256]
    {
      float acc[49];
      #pragma unroll
      for (int i = 0; i < 49; i++) acc[i] = 0.f;
      for (int c0 = 0; c0 < 64; c0 += 4) {
        __syncthreads();   // first iter also fences conv2's fm2s writes
        for (int i = tid; i < 256 * 36; i += 256) {
          int oo = i / 36, j = i - oo * 36;
          ws4p[oo * 37 + j] = c3w[oo * 576 + c0 * 9 + j];
        }
        __syncthreads();
        for (int cc = 0; cc < 4; cc++)
          for (int ky = 0; ky < 3; ky++)
            for (int kx = 0; kx < 3; kx++) {
              float wgt = ws4p[tid * 37 + cc * 9 + ky * 3 + kx];
              const float* xp = &fm2s[(c0 + cc) * 81 + ky * 9 + kx];
              #pragma unroll
              for (int yy = 0; yy < 7; yy++)
                #pragma unroll
                for (int xx = 0; xx < 7; xx++)
                  acc[yy * 7 + xx] += wgt * xp[yy * 9 + xx];
            }
      }
      float bo = c3b[tid];
      for (int i = 0; i < 49; i++) {
        float v = fmaxf(acc[i] + bo, 0.f);
        vecs[((long)f * 49 + i) * 256 + tid] = v;
        vecs_s[i * 256 + tid] = v;
      }
    }
    __syncthreads();

    // aprep: A = vecs @ W1^T + b1
    {
      float acc2[49];
      #pragma unroll
      for (int i = 0; i < 49; i++) acc2[i] = 0.f;
      for (int k = 0; k < 256; k++) {
        float wgt = w1t[k * 256 + tid];
        #pragma unroll
        for (int i = 0; i < 49; i++) acc2[i] += vecs_s[i * 256 + k] * wgt;
      }
      float bb = ab1[tid];
      for (int i = 0; i < 49; i++)
        A[((long)f * 49 + i) * 256 + tid] = acc2[i] + bb;
    }
    __syncthreads();  // compiler drains vmcnt before barrier: all stores done
    if (tid == 0)
      __hip_atomic_store(&flags[f], (unsigned long long)(f + 1),
                         __ATOMIC_RELEASE, __HIP_MEMORY_SCOPE_AGENT);
    return;
  }

  // ================= SCAN: R13 body, B1 deleted via col-major staging ======
  const int w = (int)blockIdx.x;    // worker 0..7
  const int lane = tid & 63;
  const int wv = tid >> 6;          // wave 0..3 (= LSTM gate id)
  const int quad = lane >> 4;
  const int l15 = lane & 15;
  const int r0 = 6 * w;                       // attention rows [r0, r0+nr)
  const int nr = (w < 7) ? 6 : 7;             // 7*6 + 7 = 49
  const int prow = tid >> 5;        // 0..7: softmax row
  const int pcol = (tid & 31) * 8;  // 8 contiguous cols (softmax/ctx)

  for (int i = tid; i < 16 * 264; i += 256) (&Ss[0][0])[i] = (__bf16)0.f;
  for (int i = tid; i < 8 * HID; i += 256) (&cxp[0][0])[i] = 0.f;
  b2s[tid] = b2g[tid];
  hbf[tid] = (__bf16)0.f;
  float cbias[4];
  if (tid < 32) {
    #pragma unroll
    for (int g = 0; g < 4; g++) {
      int row = 256 * g + 32 * w + tid;
      cbias[g] = bihg[row] + bhhg[row];
    }
  }
  float creg = 0.f;  // cell state, tid<32 owns dim 32*w+tid
  float hreg = 0.f;  // own h dim (tid), updated by per-thread poll

  // ---- register-resident MFMA B-fragments ----
  v8bf BW2[4][8];
  #pragma unroll
  for (int ntl = 0; ntl < 4; ntl++) {
    const int row = wv * 64 + ntl * 16 + l15;
    #pragma unroll
    for (int k = 0; k < 8; k++)
      BW2[ntl][k] = *(const v8bf*)(w2b + row * 256 + k * 32 + quad * 8);
  }
  v8bf BIH[2][8], BHH[2][8];
  #pragma unroll
  for (int nt = 0; nt < 2; nt++) {
    const int row = 256 * wv + 32 * w + nt * 16 + l15;
    #pragma unroll
    for (int k = 0; k < 8; k++) {
      BIH[nt][k] = *(const v8bf*)(wihb + row * 256 + k * 32 + quad * 8);
      BHH[nt][k] = *(const v8bf*)(whhb + row * 256 + k * 32 + quad * 8);
    }
  }
  __syncthreads();

  int ready = 0;  // frames confirmed produced

  for (int t = 0; t < T_FRAMES; t++) {
    // ---- watermark: confirm frames [t, t+64) produced (once per 64 steps) --
    if (t >= ready) {
      int idx = t + lane; if (idx > T_FRAMES - 1) idx = T_FRAMES - 1;
      const unsigned long long want = (unsigned long long)(idx + 1);
      unsigned long long fv =
          __hip_atomic_load(&flags[idx], __ATOMIC_RELAXED, __HIP_MEMORY_SCOPE_AGENT);
      int gd = 0;
      while (!__all(fv == want) && ++gd < 5000000) {
        __builtin_amdgcn_s_sleep(8);
        fv = __hip_atomic_load(&flags[idx], __ATOMIC_RELAXED, __HIP_MEMORY_SCOPE_AGENT);
      }
      (void)__hip_atomic_load(&flags[idx], __ATOMIC_ACQUIRE, __HIP_MEMORY_SCOPE_AGENT);
      ready = t + 64;
    }

    // issue this step's A loads: column tid of rows r0..r0+6 (fly during h wait)
    float areg[7];
    {
      const float* Ab = A + ((long)t * NI + r0) * HID + tid;
      #pragma unroll
      for (int i = 0; i < 7; i++) areg[i] = Ab[i * HID];
    }
    // vecs loads for the softmax/ctx phase (row = prow, cols pcol..pcol+7)
    int rr = r0 + prow; if (rr > 48) rr = 48;
    const float* Vp = vecs + ((long)t * NI + rr) * HID + pcol;
    const float4 v40 = *(const float4*)(Vp);
    const float4 v41 = *(const float4*)(Vp + 4);

    if (t > 0) {  // per-thread poll of own h word: (seq<<32)|f32bits
      const unsigned tgt = (unsigned)t;
      unsigned long long pk =
          __hip_atomic_load(&hbuf[tid], __ATOMIC_RELAXED, __HIP_MEMORY_SCOPE_AGENT);
      int gd = 0;
      while ((unsigned)(pk >> 32) < tgt && ++gd < 5000000) {
        __builtin_amdgcn_s_sleep(1);
        pk = __hip_atomic_load(&hbuf[tid], __ATOMIC_RELAXED, __HIP_MEMORY_SCOPE_AGENT);
      }
      hreg = __uint_as_float((unsigned)pk);
      hbf[tid] = (__bf16)hreg;   // fenced by B2 before any use (after B6)
      // NO barrier: staging needs only this thread's own hreg
    }

    // stage s = tanh(A + h), column-major: Ss[i][tid], i = local row
    #pragma unroll
    for (int i = 0; i < 7; i++)
      if (i < nr) Ss[i][tid] = (__bf16)tanh_fast(areg[i] + hreg);
    __syncthreads();  // B2: Ss (and hbf) ready

    // logits = s @ W2^T + b2 (rows 0..7 valid)
    v4f acc[4];
    #pragma unroll
    for (int ntl = 0; ntl < 4; ntl++) acc[ntl] = (v4f){0.f, 0.f, 0.f, 0.f};
    #pragma unroll
    for (int k = 0; k < 8; k++) {
      const v8bf av = *(const v8bf*)&Ss[l15][k * 32 + quad * 8];
      #pragma unroll
      for (int ntl = 0; ntl < 4; ntl++)
        acc[ntl] = __builtin_amdgcn_mfma_f32_16x16x32_bf16(av, BW2[ntl][k], acc[ntl], 0, 0, 0);
    }
    if (quad < 2) {
      #pragma unroll
      for (int ntl = 0; ntl < 4; ntl++) {
        const int col = wv * 64 + ntl * 16 + l15;
        const float bb = b2s[col];
        #pragma unroll
        for (int reg = 0; reg < 4; reg++)
          Wt[quad * 4 + reg][col] = acc[ntl][reg] + bb;
      }
    }
    __syncthreads();  // B3

    // softmax + ctx products (invalid rows stay zero)
    if (prow < nr) {
      float x[8];
      *(float4*)&x[0] = *(const float4*)&Wt[prow][pcol];
      *(float4*)&x[4] = *(const float4*)&Wt[prow][pcol + 4];
      float m = x[0];
      #pragma unroll
      for (int i = 1; i < 8; i++) m = fmaxf(m, x[i]);
      #pragma unroll
      for (int off = 16; off; off >>= 1) m = fmaxf(m, __shfl_xor(m, off, 64));
      float e[8], sm = 0.f;
      #pragma unroll
      for (int i = 0; i < 8; i++) { e[i] = __expf(x[i] - m); sm += e[i]; }
      #pragma unroll
      for (int off = 16; off; off >>= 1) sm += __shfl_xor(sm, off, 64);
      const float inv = __builtin_amdgcn_rcpf(sm);
      cxp[prow][pcol + 0] = e[0] * inv * v40.x;
      cxp[prow][pcol + 1] = e[1] * inv * v40.y;
      cxp[prow][pcol + 2] = e[2] * inv * v40.z;
      cxp[prow][pcol + 3] = e[3] * inv * v40.w;
      cxp[prow][pcol + 4] = e[4] * inv * v41.x;
      cxp[prow][pcol + 5] = e[5] * inv * v41.y;
      cxp[prow][pcol + 6] = e[6] * inv * v41.z;
      cxp[prow][pcol + 7] = e[7] * inv * v41.w;
    }
    __syncthreads();  // B5

    // channel sum -> bf16 pack -> publish u64 (seq | 2×bf16)
    float cp = 0.f;
    #pragma unroll
    for (int r = 0; r < 8; r++) cp += cxp[r][tid];
    float cpo = __shfl_xor(cp, 1, 64);
    if ((tid & 1) == 0) {
      union { __bf16 b; unsigned short s; } lo, hi;
      lo.b = (__bf16)cp; hi.b = (__bf16)cpo;
      unsigned word = ((unsigned)hi.s << 16) | (unsigned)lo.s;
      unsigned long long pk =
          ((unsigned long long)(unsigned)(t + 1) << 32) | (unsigned long long)word;
      __hip_atomic_store(&cpub[w * 128 + (tid >> 1)], pk, __ATOMIC_RELAXED, __HIP_MEMORY_SCOPE_AGENT);
      cpl[tid >> 1] = word;
    }
    __syncthreads();  // B6

    // h @ Whh^T chain — runs while remote publishes land
    v4f gacc[2];
    gacc[0] = (v4f){0.f, 0.f, 0.f, 0.f};
    gacc[1] = (v4f){0.f, 0.f, 0.f, 0.f};
    #pragma unroll
    for (int k = 0; k < 8; k++) {
      v8bf hf;
      #pragma unroll
      for (int z = 0; z < 8; z++) hf[z] = (__bf16)0.f;
      if (l15 == 0) hf = *(const v8bf*)&hbf[k * 32 + quad * 8];
      gacc[0] = __builtin_amdgcn_mfma_f32_16x16x32_bf16(hf, BHH[0][k], gacc[0], 0, 0, 0);
      gacc[1] = __builtin_amdgcn_mfma_f32_16x16x32_bf16(hf, BHH[1][k], gacc[1], 0, 0, 0);
    }

    // uniform poll-gather of remote ctx partials (last iteration == the data)
    unsigned long long g[8][4];
    const unsigned ctgt = (unsigned)(t + 1);
    const bool remote = (l15 < NWG) && (l15 != w);
    {
      int gd = 0;
      while (true) {
        bool ok = true;
        if (remote) {
          const unsigned long long* src = cpub + l15 * 128 + quad * 4;
          #pragma unroll
          for (int k = 0; k < 8; k++)
            #pragma unroll
            for (int q2 = 0; q2 < 4; q2++) {
              g[k][q2] = __hip_atomic_load(&src[k * 16 + q2], __ATOMIC_RELAXED, __HIP_MEMORY_SCOPE_AGENT);
              ok &= ((unsigned)(g[k][q2] >> 32) >= ctgt);
            }
        }
        if (__all(ok) || ++gd > 5000000) break;
        __builtin_amdgcn_s_sleep(1);
      }
    }

    // P rows as MFMA A-frags; accumulate
    #pragma unroll
    for (int k = 0; k < 8; k++) {
      union { unsigned u[4]; v8bf v; } pf;
      if (remote) {
        pf.u[0] = (unsigned)g[k][0]; pf.u[1] = (unsigned)g[k][1];
        pf.u[2] = (unsigned)g[k][2]; pf.u[3] = (unsigned)g[k][3];
      } else if (l15 == w) {
        pf.u[0] = cpl[k * 16 + quad * 4 + 0];
        pf.u[1] = cpl[k * 16 + quad * 4 + 1];
        pf.u[2] = cpl[k * 16 + quad * 4 + 2];
        pf.u[3] = cpl[k * 16 + quad * 4 + 3];
      } else {
        pf.u[0] = pf.u[1] = pf.u[2] = pf.u[3] = 0u;
      }
      gacc[0] = __builtin_amdgcn_mfma_f32_16x16x32_bf16(pf.v, BIH[0][k], gacc[0], 0, 0, 0);
      gacc[1] = __builtin_amdgcn_mfma_f32_16x16x32_bf16(pf.v, BIH[1][k], gacc[1], 0, 0, 0);
    }
    #pragma unroll
    for (int nt = 0; nt < 2; nt++) {
      float tot = gacc[nt][0] + gacc[nt][1] + gacc[nt][2] + gacc[nt][3];
      tot += __shfl_xor(tot, 16, 64);
      tot += __shfl_xor(tot, 32, 64);
      if (lane < 16) gb[wv][nt * 16 + lane] = tot;
    }
    __syncthreads();  // B7

    // cell update; publish h slice as (seq | f32bits)
    if (tid < 32) {
      float gi = gb[0][tid] + cbias[0];
      float gf = gb[1][tid] + cbias[1];
      float gg = gb[2][tid] + cbias[2];
      float go = gb[3][tid] + cbias[3];
      float si = sigm_fast(gi);
      float sf = sigm_fast(gf);
      float so = sigm_fast(go);
      creg = sf * creg + si * tanh_fast(gg);
      float hn = so * tanh_fast(creg);
      unsigned long long pk = ((unsigned long long)(unsigned)(t + 1) << 32) |
                              (unsigned long long)__float_as_uint(hn);
      __hip_atomic_store(&hbuf[32 * w + tid], pk, __ATOMIC_RELAXED, __HIP_MEMORY_SCOPE_AGENT);
    }
  }

  // q = h_T @ q_w^T + q_b
  if (w == 0) {
    const unsigned tgt = (unsigned)T_FRAMES;
    unsigned long long pk =
        __hip_atomic_load(&hbuf[tid], __ATOMIC_RELAXED, __HIP_MEMORY_SCOPE_AGENT);
    int gd = 0;
    while ((unsigned)(pk >> 32) < tgt && ++gd < 5000000) {
      __builtin_amdgcn_s_sleep(1);
      pk = __hip_atomic_load(&hbuf[tid], __ATOMIC_RELAXED, __HIP_MEMORY_SCOPE_AGENT);
    }
    hs[tid] = __uint_as_float((unsigned)pk);
    __syncthreads();
    if (tid < NA) {
      float acc = qb[tid];
      for (int k = 0; k < HID; k++) acc += hs[k] * qw[tid * HID + k];
      out[tid] = acc;
    }
  }
}

extern "C" void kernel_launch(void* const* d_in, const int* in_sizes, int n_in,
                              void* d_out, int out_size, void* d_ws, size_t ws_size,
                              hipStream_t stream) {
  const float* frames = (const float*)d_in[0];
  const float* c1w = (const float*)d_in[1];
  const float* c1b = (const float*)d_in[2];
  const float* c2w = (const float*)d_in[3];
  const float* c2b = (const float*)d_in[4];
  const float* c3w = (const float*)d_in[5];
  const float* c3b = (const float*)d_in[6];
  const float* aw1 = (const float*)d_in[7];
  const float* ab1 = (const float*)d_in[8];
  const float* aw2 = (const float*)d_in[9];
  const float* ab2 = (const float*)d_in[10];
  const float* wih = (const float*)d_in[11];
  const float* whh = (const float*)d_in[12];
  const float* bih = (const float*)d_in[13];
  const float* bhh = (const float*)d_in[14];
  const float* qw  = (const float*)d_in[15];
  const float* qb  = (const float*)d_in[16];

  char* ws = (char*)d_ws;
  float*  A     = (float*)(ws + OFF_FM1);
  float*  vecs  = (float*)(ws + OFF_VECS);
  __bf16* w2b   = (__bf16*)(ws + OFF_W2B);
  __bf16* wihb  = (__bf16*)(ws + OFF_WIHB);
  __bf16* whhb  = (__bf16*)(ws + OFF_WHHB);
  float*  w1t   = (float*)(ws + OFF_W1T);
  unsigned long long* comm = (unsigned long long*)(ws + OFF_COMM);
  unsigned long long* hbuf  = comm;
  unsigned long long* cpub  = comm + 256;
  unsigned long long* flags = comm + 1280;

  prep_weights<<<256, 256, 0, stream>>>(aw2, wih, whh, aw1, w2b, wihb, whhb, w1t, comm);
  mega_k<<<8 + T_FRAMES, 256, 0, stream>>>(
      frames, c1w, c1b, c2w, c2b, c3w, c3b, w1t, ab1,
      A, vecs, w2b, wihb, whhb, ab2, bih, bhh, qw, qb,
      hbuf, cpub, flags, (float*)d_out);
}